// Round 4
// baseline (9046.387 us; speedup 1.0000x reference)
//
#include <hip/hip_runtime.h>

#define S_LEN 256
// ws float offsets
#define GI_OFF     0u           // [256][2048][32]  x@Wih + bih + bhh, [s][col][n]
#define VAL_OFF    16777216u    // [256][32][256]   x@Wv + bv
#define KEY_OFF    18874368u    // [256][32][256]   unitnorm(x@Wk + bk)
#define ROT_OFF    20971520u    // [256][256][32]   read_outs transposed
#define HT_OFF     23068672u    // [2][512][32]     h double-buffered, [d][n] (LSTM staging layout)
#define HTAPE_OFF  23101440u    // [256][32][512]   h full history, [t][n][d] (tape consumption layout)
#define WAQT_OFF   27295744u    // [296][768]       fused action+query weights, row-major per output
#define BAQ_OFF    27523072u    // [296] biases (padded to 512)
#define FLG_OFF    27523584u    // 128 LSTM flags, stride 16 u32 (64B) each
#define WS_TOTAL   27525632u    // ~110 MB

#define DYN_LDS 73984

// ---- agent-scope coherent helpers (validated R3): bypass stale L2, hit the LLC ----
__device__ __forceinline__ float2 coh_ld2(const float* p) {
  union { unsigned long long u; float2 f; } cv;
  cv.u = __hip_atomic_load((unsigned long long*)p, __ATOMIC_RELAXED, __HIP_MEMORY_SCOPE_AGENT);
  return cv.f;
}
__device__ __forceinline__ void coh_st(float* p, float v) {
  __hip_atomic_store(p, v, __ATOMIC_RELAXED, __HIP_MEMORY_SCOPE_AGENT);
}

// Wait until all 128 LSTM flags >= tgt. Contention-free: each flag on its own 64B line.
__device__ __forceinline__ void wait_flags(unsigned* f, int tid, unsigned tgt) {
  if (tid < 64) {
    while (true) {
      unsigned a = __hip_atomic_load(f + (2 * tid) * 16, __ATOMIC_RELAXED, __HIP_MEMORY_SCOPE_AGENT);
      unsigned b = __hip_atomic_load(f + (2 * tid + 1) * 16, __ATOMIC_RELAXED, __HIP_MEMORY_SCOPE_AGENT);
      if (__all((a >= tgt) && (b >= tgt))) break;
      __builtin_amdgcn_s_sleep(1);
    }
  }
}

// ---- parallel pre-pass: gi = x@Wih + bih + bhh ; values = x@Wv+bv ; keys_raw = x@Wk+bk ----
__global__ __launch_bounds__(256) void k_pre(const float* __restrict__ inp,
    const float* __restrict__ Wih, const float* __restrict__ bih, const float* __restrict__ bhh,
    const float* __restrict__ Wv, const float* __restrict__ bv,
    const float* __restrict__ Wk, const float* __restrict__ bk, float* __restrict__ ws)
{
  __shared__ __align__(16) float xs[256 * 32];
  const int s = blockIdx.x / 10, tile = blockIdx.x % 10;
  const int tid = threadIdx.x;
  const float* W; int C, c;
  if (tile < 8)       { W = Wih; C = 2048; c = tile * 256 + tid; }
  else if (tile == 8) { W = Wv;  C = 256;  c = tid; }
  else                { W = Wk;  C = 256;  c = tid; }

  float acc[32];
#pragma unroll
  for (int n = 0; n < 32; ++n) acc[n] = 0.f;

  for (int p = 0; p < 2; ++p) {
    __syncthreads();
    for (int w = 0; w < 32; ++w) {
      int i = tid + w * 256;
      int k = i & 255, n = i >> 8;
      float v = inp[s * 16384 + n * 512 + p * 256 + k];
      int pos = ((((n >> 2) + (k & 7)) & 7) << 2) | (n & 3);
      xs[k * 32 + pos] = v;
    }
    __syncthreads();
    const float* Wp = W + (size_t)(p * 256) * C + c;
#pragma unroll 8
    for (int kk = 0; kk < 256; ++kk) {
      float wv = Wp[(size_t)kk * C];
      const float4* row = (const float4*)(xs + kk * 32);
#pragma unroll
      for (int j = 0; j < 8; ++j) {
        float4 a = row[(j + (kk & 7)) & 7];
        acc[4 * j + 0] = fmaf(a.x, wv, acc[4 * j + 0]);
        acc[4 * j + 1] = fmaf(a.y, wv, acc[4 * j + 1]);
        acc[4 * j + 2] = fmaf(a.z, wv, acc[4 * j + 2]);
        acc[4 * j + 3] = fmaf(a.w, wv, acc[4 * j + 3]);
      }
    }
  }

  if (tile < 8) {
    float bb = bih[c] + bhh[c];
    float4* dst = (float4*)(ws + GI_OFF + (size_t)s * 65536 + (size_t)c * 32);
#pragma unroll
    for (int j = 0; j < 8; ++j)
      dst[j] = make_float4(acc[4 * j] + bb, acc[4 * j + 1] + bb, acc[4 * j + 2] + bb, acc[4 * j + 3] + bb);
  } else {
    unsigned base = (tile == 8) ? VAL_OFF : KEY_OFF;
    float bb = (tile == 8) ? bv[c] : bk[c];
#pragma unroll
    for (int n = 0; n < 32; ++n)
      ws[base + (size_t)s * 8192 + n * 256 + c] = acc[n] + bb;
  }
}

__global__ __launch_bounds__(256) void k_knorm(float* __restrict__ ws) {
  int b = blockIdx.x;
  int m = threadIdx.x;
  float* p = ws + KEY_OFF + (size_t)b * 256;
  float x = p[m];
  float ss = x * x;
#pragma unroll
  for (int off = 32; off > 0; off >>= 1) ss += __shfl_xor(ss, off, 64);
  p[m] = x / fmaxf(sqrtf(ss), 1e-12f);
}

// Build fused action+query weight table WAQT[296][768] (+ biases BAQ[296]).
// o = tp*74 + j ; j<10 -> action col tp*10+j ; else query col tp*64+(j-10)
__global__ __launch_bounds__(256) void k_prep_waq(const float* __restrict__ Wa, const float* __restrict__ ba,
                                                  const float* __restrict__ Wq, const float* __restrict__ bq,
                                                  float* __restrict__ ws) {
  int o = blockIdx.x;
  int k = blockIdx.y * 256 + threadIdx.x;
  int tp = o / 74, j = o - tp * 74;
  float v = (j < 10) ? Wa[k * 40 + tp * 10 + j] : Wq[k * 256 + tp * 64 + (j - 10)];
  ws[WAQT_OFF + (size_t)o * 768 + k] = v;
  if (k == 0) ws[BAQ_OFF + o] = (j < 10) ? ba[tp * 10 + j] : bq[tp * 64 + (j - 10)];
}

struct TDS {
  float tape[4][32][64];   // 8192
  float tkey[4][32][64];   // 8192
  float har[768];
  float vs[256], ks2[256];
  float ro[256];
  float act[4][12];
  float q[4][64];
  float rpos[4][32], wpos[4][32];
};

__global__ __launch_bounds__(256) void nam_coop(
    const float* __restrict__ Whh, float* __restrict__ ws, float* __restrict__ out)
{
  extern __shared__ float smem[];
  const int blk = blockIdx.x, tid = threadIdx.x;
  unsigned* flg = (unsigned*)(ws + FLG_OFF);

  if (blk < 128) {
    // ================= LSTM block: 16 gate-cols, persistent Whh in VGPRs =================
    float* hs = smem;                       // [512 rows][32 n], XOR-swizzled float4 chunks
    float (*sg)[33] = (float(*)[33])(smem + 16384);
    const int ks = tid & 15, cs = tid >> 4;
    const int dd = cs & 3, g4 = cs >> 2;
    const int col = g4 * 512 + blk * 4 + dd;
    const int dfin = tid >> 5, nfin = tid & 31;
    float w[32];
#pragma unroll
    for (int kk = 0; kk < 32; ++kk)
      w[kk] = Whh[(size_t)(kk * 16 + ks) * 2048 + col];
    float creg = 0.f;

    for (int t = 0; t < S_LEN; ++t) {
      // gi prefetch (plain cached loads; independent of flags)
      float gic[4] = {0.f, 0.f, 0.f, 0.f};
      if (tid < 128) {
#pragma unroll
        for (int g = 0; g < 4; ++g)
          gic[g] = ws[GI_OFF + (size_t)t * 65536 + (size_t)(g * 512 + blk * 4 + dfin) * 32 + nfin];
      }
      if (t > 0) wait_flags(flg, tid, (unsigned)t);
      __syncthreads();
      // stage full h_{t-1} (64 KB) from LLC, XOR-swizzled
      const float* hsrc = ws + HT_OFF + ((t + 1) & 1) * 16384;
#pragma unroll
      for (int w2 = 0; w2 < 32; ++w2) {
        int i2 = tid + w2 * 256;
        float2 v = coh_ld2(hsrc + 2 * i2);
        int r = i2 >> 4, j2 = i2 & 15;
        int pos = ((((j2 >> 1) ^ (r & 7)) << 1) | (j2 & 1));
        ((float2*)hs)[r * 16 + pos] = v;
      }
      __syncthreads();
      float acc[32];
#pragma unroll
      for (int n = 0; n < 32; ++n) acc[n] = 0.f;
#pragma unroll
      for (int kk = 0; kk < 32; ++kk) {
        int r = kk * 16 + ks;
        float wv = w[kk];
        const float4* row = (const float4*)hs + r * 8;
#pragma unroll
        for (int j = 0; j < 8; ++j) {
          float4 a = row[j ^ (r & 7)];
          acc[4 * j + 0] = fmaf(a.x, wv, acc[4 * j + 0]);
          acc[4 * j + 1] = fmaf(a.y, wv, acc[4 * j + 1]);
          acc[4 * j + 2] = fmaf(a.z, wv, acc[4 * j + 2]);
          acc[4 * j + 3] = fmaf(a.w, wv, acc[4 * j + 3]);
        }
      }
#pragma unroll
      for (int n = 0; n < 32; ++n) {
        float v = acc[n];
        v += __shfl_down(v, 8, 16);
        v += __shfl_down(v, 4, 16);
        v += __shfl_down(v, 2, 16);
        v += __shfl_down(v, 1, 16);
        acc[n] = v;
      }
      if (ks == 0) {
#pragma unroll
        for (int n = 0; n < 32; ++n) sg[cs][n] = acc[n];
      }
      __syncthreads();
      if (tid < 128) {
        float gv[4];
#pragma unroll
        for (int g = 0; g < 4; ++g) gv[g] = sg[g * 4 + dfin][nfin] + gic[g];
        float si = 1.f / (1.f + expf(-gv[0]));
        float sf = 1.f / (1.f + expf(-gv[1]));
        float so = 1.f / (1.f + expf(-gv[3]));
        float cn = sf * creg + si * tanhf(gv[2]);
        float hn = so * tanhf(cn);
        creg = cn;
        int dg = blk * 4 + dfin;
        coh_st(ws + HT_OFF + (t & 1) * 16384 + dg * 32 + nfin, hn);
        coh_st(ws + HTAPE_OFF + (size_t)t * 16384 + nfin * 512 + dg, hn);
      }
      __syncthreads();   // drains all waves' vmcnt -> h stores at LLC before flag
      if (tid == 0)
        __hip_atomic_store(flg + blk * 16, (unsigned)(t + 1), __ATOMIC_RELAXED, __HIP_MEMORY_SCOPE_AGENT);
    }
  } else {
    // ================= tape block: one batch row n, all 4 tapes, fully block-local =================
    TDS* td = (TDS*)smem;
    const int n = blk - 128;
    const int wv = tid >> 6, ln = tid & 63;
    for (int i = tid; i < 8192; i += 256) {
      ((float*)td->tape)[i] = 0.f;
      ((float*)td->tkey)[i] = 0.f;
    }
    if (tid < 256) td->ro[tid] = 0.f;
    if (tid < 128) { td->rpos[tid >> 5][tid & 31] = ((tid & 31) == 0) ? 1.f : 0.f; }
    else if (tid < 256) { int q2 = tid - 128; td->wpos[q2 >> 5][q2 & 31] = ((q2 & 31) == 0) ? 1.f : 0.f; }
    __syncthreads();

    for (int tau = 0; tau < S_LEN; ++tau) {
      // v/k loads first (flag-independent, overlap the poll)
      float vreg = ws[VAL_OFF + (size_t)tau * 8192 + n * 256 + tid];
      float kreg = ws[KEY_OFF + (size_t)tau * 8192 + n * 256 + tid];
      wait_flags(flg, tid, (unsigned)(tau + 1));
      __syncthreads();
      // stage har = [h_tau (LLC), ro (LDS)] + v/k
      {
        float2 hv = coh_ld2(ws + HTAPE_OFF + (size_t)tau * 16384 + n * 512 + 2 * tid);
        ((float2*)td->har)[tid] = hv;
        td->har[512 + tid] = td->ro[tid];
        td->vs[tid] = vreg;
        td->ks2[tid] = kreg;
      }
      __syncthreads();
      // fused action+query GEMM: 296 outputs, full K=768 per thread
      for (int o = tid; o < 296; o += 256) {
        const float4* wrow = (const float4*)(ws + WAQT_OFF + (size_t)o * 768);
        const float4* h4 = (const float4*)td->har;
        float p = 0.f;
#pragma unroll 8
        for (int j = 0; j < 192; ++j) {
          float4 a = wrow[j], b = h4[j];
          p += a.x * b.x + a.y * b.y + a.z * b.z + a.w * b.w;
        }
        p += ws[BAQ_OFF + o];
        int tp = o / 74, j2 = o - tp * 74;
        if (j2 < 10) td->act[tp][j2] = p;
        else         td->q[tp][j2 - 10] = p;
      }
      __syncthreads();
      // per-wave tape ops: wave wv owns tape wv, lane ln = channel c
      {
        float a0 = td->act[wv][0], a1 = td->act[wv][1], a2 = td->act[wv][2], a3 = td->act[wv][3];
        float mx = fmaxf(fmaxf(a0, a1), fmaxf(a2, a3));
        float e0 = expf(a0 - mx), e1 = expf(a1 - mx), e2 = expf(a2 - mx), e3 = expf(a3 - mx);
        float inv = 1.f / (e0 + e1 + e2 + e3);
        float rd0 = e0 * inv, rd1 = e1 * inv, rd2 = e2 * inv, rd3 = e3 * inv;
        a0 = td->act[wv][4]; a1 = td->act[wv][5]; a2 = td->act[wv][6]; a3 = td->act[wv][7];
        mx = fmaxf(fmaxf(a0, a1), fmaxf(a2, a3));
        e0 = expf(a0 - mx); e1 = expf(a1 - mx); e2 = expf(a2 - mx); e3 = expf(a3 - mx);
        inv = 1.f / (e0 + e1 + e2 + e3);
        float wd0 = e0 * inv, wd1 = e1 * inv, wd2 = e2 * inv, wd3 = e3 * inv;
        float rw0 = 1.f / (1.f + expf(-td->act[wv][8]));
        float rw1 = 1.f / (1.f + expf(-td->act[wv][9]));

        float vv = td->vs[wv * 64 + ln];
        float kr = td->ks2[wv * 64 + ln];   // already unit-normalized in pre-pass
        float ov = 0.f, ok = 0.f;
#pragma unroll
        for (int l = 0; l < 32; ++l) {
          float wp = td->wpos[wv][l];
          ov = fmaf(td->tape[wv][l][ln], wp, ov);
          ok = fmaf(td->tkey[wv][l][ln], wp, ok);
        }
        float dv = (vv - ov) * rw1, dk = (kr - ok) * rw1;
        float roacc = 0.f;
#pragma unroll
        for (int l = 0; l < 32; ++l) {
          float wp = td->wpos[wv][l];
          float tv = td->tape[wv][l][ln] + wp * dv;
          td->tape[wv][l][ln] = tv;
          td->tkey[wv][l][ln] += wp * dk;
          roacc = fmaf(tv, td->rpos[wv][l], roacc);
        }
        float roval = roacc * rw0;
        // jpos: lane l<32 computes full dot over c with staggered (conflict-free) access
        float jp = 0.f;
        if (ln < 32) {
#pragma unroll 8
          for (int i = 0; i < 64; ++i) {
            int cc = (ln + i) & 63;
            jp = fmaf(td->tkey[wv][ln][cc], td->q[wv][cc], jp);
          }
        }
        float ssj = jp * jp;
#pragma unroll
        for (int off = 16; off > 0; off >>= 1) ssj += __shfl_xor(ssj, off, 32);
        if (ln < 32) {
          float jn = jp / fmaxf(sqrtf(ssj), 1e-12f);
          float rp = td->rpos[wv][ln], wp = td->wpos[wv][ln];
          float prv = td->rpos[wv][(ln + 1) & 31];
          float nxt = td->rpos[wv][(ln + 31) & 31];
          td->wpos[wv][ln] = prv * wd0 + wp * wd1 + nxt * wd2 + jn * wd3;
          td->rpos[wv][ln] = prv * rd0 + rp * rd1 + nxt * rd2 + jn * rd3;
        }
        td->ro[wv * 64 + ln] = roval;
        ws[ROT_OFF + (size_t)tau * 8192 + (wv * 64 + ln) * 32 + n] = roval;
      }
      __syncthreads();
    }
    // final tape write-out
    for (int i = tid; i < 8192; i += 256) {
      int l = i >> 8, r2 = i & 255, tp = r2 >> 6, cc = r2 & 63;
      out[4194304 + (size_t)(l * 32 + n) * 256 + tp * 64 + cc] = td->tape[tp][l][cc];
    }
  }
}

__global__ __launch_bounds__(256) void k_out_gemm(const float* __restrict__ roT, const float* __restrict__ Wo,
                                                  const float* __restrict__ bo, float* __restrict__ out) {
  int s = blockIdx.x >> 1, dh = blockIdx.x & 1;
  int d = dh * 256 + threadIdx.x;
  const float* rb = roT + (size_t)s * 8192;
  float acc[32];
#pragma unroll
  for (int n = 0; n < 32; ++n) acc[n] = 0.f;
  for (int m = 0; m < 256; ++m) {
    float w = Wo[m * 512 + d];
    const float4* rc = (const float4*)(rb + m * 32);
#pragma unroll
    for (int j = 0; j < 8; ++j) {
      float4 r4 = rc[j];
      acc[4 * j + 0] = fmaf(r4.x, w, acc[4 * j + 0]);
      acc[4 * j + 1] = fmaf(r4.y, w, acc[4 * j + 1]);
      acc[4 * j + 2] = fmaf(r4.z, w, acc[4 * j + 2]);
      acc[4 * j + 3] = fmaf(r4.w, w, acc[4 * j + 3]);
    }
  }
  float bd = bo[d];
#pragma unroll
  for (int n = 0; n < 32; ++n) out[(size_t)(s * 32 + n) * 512 + d] = acc[n] + bd;
}

extern "C" void kernel_launch(void* const* d_in, const int* in_sizes, int n_in,
                              void* d_out, int out_size, void* d_ws, size_t ws_size,
                              hipStream_t stream) {
  const float* inp = (const float*)d_in[0];
  const float* Wih = (const float*)d_in[1];
  const float* Whh = (const float*)d_in[2];
  const float* bih = (const float*)d_in[3];
  const float* bhh = (const float*)d_in[4];
  const float* Wa  = (const float*)d_in[5];
  const float* ba  = (const float*)d_in[6];
  const float* Wv  = (const float*)d_in[7];
  const float* bv  = (const float*)d_in[8];
  const float* Wk  = (const float*)d_in[9];
  const float* bk  = (const float*)d_in[10];
  const float* Wq  = (const float*)d_in[11];
  const float* bq  = (const float*)d_in[12];
  const float* Wo  = (const float*)d_in[13];
  const float* bo  = (const float*)d_in[14];
  float* ws = (float*)d_ws;
  float* out = (float*)d_out;

  static bool attr_set = false;
  if (!attr_set) {
    hipFuncSetAttribute((const void*)nam_coop, hipFuncAttributeMaxDynamicSharedMemorySize, DYN_LDS);
    attr_set = true;
  }

  hipMemsetAsync(ws + HT_OFF, 0, 32768 * sizeof(float), stream);     // h_{-1} = 0
  hipMemsetAsync(ws + FLG_OFF, 0, 2048 * sizeof(unsigned), stream);  // flags = 0
  k_prep_waq<<<dim3(296, 3), 256, 0, stream>>>(Wa, ba, Wq, bq, ws);
  k_pre<<<2560, 256, 0, stream>>>(inp, Wih, bih, bhh, Wv, bv, Wk, bk, ws);
  k_knorm<<<8192, 256, 0, stream>>>(ws);

  void* args[] = { (void*)&Whh, (void*)&ws, (void*)&out };
  hipLaunchCooperativeKernel((void*)nam_coop, dim3(160), dim3(256), args, DYN_LDS, stream);

  k_out_gemm<<<512, 256, 0, stream>>>(ws + ROT_OFF, Wo, bo, out);
}

// Round 8
// 3346.333 us; speedup vs baseline: 2.7034x; 2.7034x over previous
//
#include <hip/hip_runtime.h>

#define S_LEN 256
// ws float offsets — TOTAL 27,519,488 floats = 110.08 MB (< R4's proven 110.1 MB)
#define GI_OFF     0u           // [256][2048][32]  x@Wih + bih + bhh, [s][col][n]
#define VAL_OFF    16777216u    // [256][32][256]   x@Wv + bv
#define KEY_OFF    18874368u    // [256][32][256]   unitnorm(x@Wk + bk)
#define HTA_OFF    20971520u    // [257][512][32]   h full history, slot t+1 = h_t, [d][n]
#define ROB_OFF    25182208u    // [257][32][256]   read_out full history, slot t+1 = ro_t
#define WAQT_OFF   27287552u    // [296][768] fused action+query weights
#define BAQ_OFF    27514880u    // [296] biases (padded 512)
#define LFLG_OFF   27515392u    // 128 LSTM flags, stride 16 u32
#define TFLG_OFF   27517440u    // 128 tape flags, stride 16 u32
#define WS_TOTAL   27519488u

// ---- agent-scope helpers: producers write through to LLC, consumers bypass stale L2 ----
__device__ __forceinline__ float coh_ld1(const float* p) {
  return __hip_atomic_load(p, __ATOMIC_RELAXED, __HIP_MEMORY_SCOPE_AGENT);
}
__device__ __forceinline__ float2 coh_ld2(const float* p) {
  union { unsigned long long u; float2 f; } cv;
  cv.u = __hip_atomic_load((const unsigned long long*)p, __ATOMIC_RELAXED, __HIP_MEMORY_SCOPE_AGENT);
  return cv.f;
}
__device__ __forceinline__ void coh_st(float* p, float v) {
  __hip_atomic_store(p, v, __ATOMIC_RELAXED, __HIP_MEMORY_SCOPE_AGENT);
}
__device__ __forceinline__ void coh_stu(unsigned* p, unsigned v) {
  __hip_atomic_store(p, v, __ATOMIC_RELAXED, __HIP_MEMORY_SCOPE_AGENT);
}
__device__ __forceinline__ unsigned coh_ldu(const unsigned* p) {
  return __hip_atomic_load(p, __ATOMIC_RELAXED, __HIP_MEMORY_SCOPE_AGENT);
}

// Wait until all 128 LSTM flags >= tgt (wave 0 polls, 2 flags/lane, 64B-strided lines)
__device__ __forceinline__ void wait_lstm_flags(const unsigned* f, int tid, unsigned tgt) {
  if (tid < 64) {
    while (true) {
      unsigned a = coh_ldu(f + (2 * tid) * 16);
      unsigned b = coh_ldu(f + (2 * tid + 1) * 16);
      if (__all((a >= tgt) && (b >= tgt))) break;
      __builtin_amdgcn_s_sleep(1);
    }
  }
}

// ---- parallel pre-pass: gi = x@Wih + bih + bhh ; values = x@Wv+bv ; keys_raw = x@Wk+bk ----
__global__ __launch_bounds__(256) void k_pre(const float* __restrict__ inp,
    const float* __restrict__ Wih, const float* __restrict__ bih, const float* __restrict__ bhh,
    const float* __restrict__ Wv, const float* __restrict__ bv,
    const float* __restrict__ Wk, const float* __restrict__ bk, float* __restrict__ ws)
{
  __shared__ __align__(16) float xs[256 * 32];
  const int s = blockIdx.x / 10, tile = blockIdx.x % 10;
  const int tid = threadIdx.x;
  const float* W; int C, c;
  if (tile < 8)       { W = Wih; C = 2048; c = tile * 256 + tid; }
  else if (tile == 8) { W = Wv;  C = 256;  c = tid; }
  else                { W = Wk;  C = 256;  c = tid; }

  float acc[32];
#pragma unroll
  for (int n = 0; n < 32; ++n) acc[n] = 0.f;

  for (int p = 0; p < 2; ++p) {
    __syncthreads();
    for (int w = 0; w < 32; ++w) {
      int i = tid + w * 256;
      int k = i & 255, n = i >> 8;
      float v = inp[s * 16384 + n * 512 + p * 256 + k];
      int pos = ((((n >> 2) + (k & 7)) & 7) << 2) | (n & 3);
      xs[k * 32 + pos] = v;
    }
    __syncthreads();
    const float* Wp = W + (size_t)(p * 256) * C + c;
#pragma unroll 8
    for (int kk = 0; kk < 256; ++kk) {
      float wv = Wp[(size_t)kk * C];
      const float4* row = (const float4*)(xs + kk * 32);
#pragma unroll
      for (int j = 0; j < 8; ++j) {
        float4 a = row[(j + (kk & 7)) & 7];
        acc[4 * j + 0] = fmaf(a.x, wv, acc[4 * j + 0]);
        acc[4 * j + 1] = fmaf(a.y, wv, acc[4 * j + 1]);
        acc[4 * j + 2] = fmaf(a.z, wv, acc[4 * j + 2]);
        acc[4 * j + 3] = fmaf(a.w, wv, acc[4 * j + 3]);
      }
    }
  }

  if (tile < 8) {
    float bb = bih[c] + bhh[c];
    float4* dst = (float4*)(ws + GI_OFF + (size_t)s * 65536 + (size_t)c * 32);
#pragma unroll
    for (int j = 0; j < 8; ++j)
      dst[j] = make_float4(acc[4 * j] + bb, acc[4 * j + 1] + bb, acc[4 * j + 2] + bb, acc[4 * j + 3] + bb);
  } else {
    unsigned base = (tile == 8) ? VAL_OFF : KEY_OFF;
    float bb = (tile == 8) ? bv[c] : bk[c];
#pragma unroll
    for (int n = 0; n < 32; ++n)
      ws[base + (size_t)s * 8192 + n * 256 + c] = acc[n] + bb;
  }
}

__global__ __launch_bounds__(256) void k_knorm(float* __restrict__ ws) {
  int b = blockIdx.x;
  int m = threadIdx.x;
  float* p = ws + KEY_OFF + (size_t)b * 256;
  float x = p[m];
  float ss = x * x;
#pragma unroll
  for (int off = 32; off > 0; off >>= 1) ss += __shfl_xor(ss, off, 64);
  p[m] = x / fmaxf(sqrtf(ss), 1e-12f);
}

// Build fused action+query weight table WAQT[296][768] (+ biases BAQ[296]).
__global__ __launch_bounds__(256) void k_prep_waq(const float* __restrict__ Wa, const float* __restrict__ ba,
                                                  const float* __restrict__ Wq, const float* __restrict__ bq,
                                                  float* __restrict__ ws) {
  int o = blockIdx.x;
  int k = blockIdx.y * 256 + threadIdx.x;
  int tp = o / 74, j = o - tp * 74;
  float v = (j < 10) ? Wa[k * 40 + tp * 10 + j] : Wq[k * 256 + tp * 64 + (j - 10)];
  ws[WAQT_OFF + (size_t)o * 768 + k] = v;
  if (k == 0) ws[BAQ_OFF + o] = (j < 10) ? ba[tp * 10 + j] : bq[tp * 64 + (j - 10)];
}

struct P1S { float hs[8192]; float sg[16][33]; };       // 32 KB half-staging + gate sums
struct DS {
  float tape[32][64]; float tkey[32][64];
  float rpos[32]; float wpos[32];
  float har[768];
  float act[12]; float q[64]; float v[64]; float kr[64];
  float dv[64]; float dk[64];
  float scrA[256]; float scrB[256];
  float norm;
};
union __align__(16) SU { P1S p; DS d; };

// Plain (non-cooperative) launch: no grid.sync anywhere — only flag-spins. All 256
// blocks are co-resident by resource math (35 KB LDS -> >=3 blocks/CU capacity,
// 256 blocks <= 256 CUs), so the spin protocol cannot deadlock.
__global__ __launch_bounds__(256) void nam_coop(
    const float* __restrict__ Whh, float* __restrict__ ws, float* __restrict__ out)
{
  __shared__ SU sm;
  const int blk = blockIdx.x, tid = threadIdx.x;
  unsigned* lflg = (unsigned*)(ws + LFLG_OFF);
  unsigned* tflg = (unsigned*)(ws + TFLG_OFF);

  if (blk < 128) {
    // ============ LSTM block: 16 gate-cols (2 per thread), weight-stationary Whh ============
    const int ks = tid & 15, cg = (tid >> 4) & 7, nh = tid >> 7;
    const int j0 = 2 * cg, j1 = 2 * cg + 1;
    const int colA = (j0 >> 2) * 512 + blk * 4 + (j0 & 3);
    const int colB = (j1 >> 2) * 512 + blk * 4 + (j1 & 3);
    float wA[32], wB[32];
#pragma unroll
    for (int kk2 = 0; kk2 < 32; ++kk2) {
      int k = (kk2 >> 4) * 256 + (kk2 & 15) * 16 + ks;   // kk2 = p*16 + kkl
      wA[kk2] = Whh[(size_t)k * 2048 + colA];
      wB[kk2] = Whh[(size_t)k * 2048 + colB];
    }
    const int dfin = tid >> 5, nfin = tid & 31;
    float creg = 0.f;

    for (int t = 0; t < S_LEN; ++t) {
      float gic[4] = {0.f, 0.f, 0.f, 0.f};
      if (tid < 128) {
#pragma unroll
        for (int g = 0; g < 4; ++g)
          gic[g] = ws[GI_OFF + (size_t)t * 65536 + (size_t)(g * 512 + blk * 4 + dfin) * 32 + nfin];
      }
      if (t > 0) wait_lstm_flags(lflg, tid, (unsigned)t);

      float acc0[16], acc1[16];
#pragma unroll
      for (int i = 0; i < 16; ++i) { acc0[i] = 0.f; acc1[i] = 0.f; }

      for (int p = 0; p < 2; ++p) {
        __syncthreads();
        // stage 256 rows (32 KB) of h_{t-1} from LLC (agent-scope), XOR-swizzled float4 layout
        const float* hsrc = ws + HTA_OFF + (size_t)t * 16384 + p * 8192;
#pragma unroll
        for (int w2 = 0; w2 < 16; ++w2) {
          int i2 = tid + w2 * 256;            // float2 index 0..4095
          float2 v = coh_ld2(hsrc + 2 * i2);
          int r = i2 >> 4, j2 = i2 & 15;
          int j4 = j2 >> 1, half = j2 & 1;
          ((float2*)sm.p.hs)[(r * 8 + (j4 ^ (r & 7))) * 2 + half] = v;
        }
        __syncthreads();
#pragma unroll
        for (int kkl = 0; kkl < 16; ++kkl) {
          int r = kkl * 16 + ks;
          const float4* row = (const float4*)sm.p.hs + r * 8;
          float4 av[4];
#pragma unroll
          for (int jj = 0; jj < 4; ++jj) av[jj] = row[((nh << 2) | jj) ^ (r & 7)];
          float w0 = wA[p * 16 + kkl], w1 = wB[p * 16 + kkl];
#pragma unroll
          for (int jj = 0; jj < 4; ++jj) {
            acc0[jj * 4 + 0] = fmaf(av[jj].x, w0, acc0[jj * 4 + 0]);
            acc0[jj * 4 + 1] = fmaf(av[jj].y, w0, acc0[jj * 4 + 1]);
            acc0[jj * 4 + 2] = fmaf(av[jj].z, w0, acc0[jj * 4 + 2]);
            acc0[jj * 4 + 3] = fmaf(av[jj].w, w0, acc0[jj * 4 + 3]);
            acc1[jj * 4 + 0] = fmaf(av[jj].x, w1, acc1[jj * 4 + 0]);
            acc1[jj * 4 + 1] = fmaf(av[jj].y, w1, acc1[jj * 4 + 1]);
            acc1[jj * 4 + 2] = fmaf(av[jj].z, w1, acc1[jj * 4 + 2]);
            acc1[jj * 4 + 3] = fmaf(av[jj].w, w1, acc1[jj * 4 + 3]);
          }
        }
      }
#pragma unroll
      for (int i = 0; i < 16; ++i) {
        float v0 = acc0[i], v1 = acc1[i];
        v0 += __shfl_down(v0, 8, 16); v1 += __shfl_down(v1, 8, 16);
        v0 += __shfl_down(v0, 4, 16); v1 += __shfl_down(v1, 4, 16);
        v0 += __shfl_down(v0, 2, 16); v1 += __shfl_down(v1, 2, 16);
        v0 += __shfl_down(v0, 1, 16); v1 += __shfl_down(v1, 1, 16);
        acc0[i] = v0; acc1[i] = v1;
      }
      if (ks == 0) {
#pragma unroll
        for (int i = 0; i < 16; ++i) {
          sm.p.sg[j0][nh * 16 + i] = acc0[i];
          sm.p.sg[j1][nh * 16 + i] = acc1[i];
        }
      }
      __syncthreads();
      if (tid < 128) {
        float gv[4];
#pragma unroll
        for (int g = 0; g < 4; ++g) gv[g] = sm.p.sg[g * 4 + dfin][nfin] + gic[g];
        float si = 1.f / (1.f + expf(-gv[0]));
        float sf = 1.f / (1.f + expf(-gv[1]));
        float so = 1.f / (1.f + expf(-gv[3]));
        float cn = sf * creg + si * tanhf(gv[2]);
        float hn = so * tanhf(cn);
        creg = cn;
        int dg = blk * 4 + dfin;
        coh_st(ws + HTA_OFF + (size_t)(t + 1) * 16384 + dg * 32 + nfin, hn);
      }
      __syncthreads();   // drains vmcnt of all waves -> h stores at LLC before flag
      if (tid == 0) coh_stu(lflg + blk * 16, (unsigned)(t + 1));
    }
  } else {
    // ============ tape block: one (n, tp) group, R3-proven step ============
    const int g = blk - 128, n = g >> 2, tpp = g & 3;
    for (int i = tid; i < 2048; i += 256) { int l = i >> 6, c = i & 63; sm.d.tape[l][c] = 0.f; sm.d.tkey[l][c] = 0.f; }
    if (tid < 32) { sm.d.rpos[tid] = (tid == 0) ? 1.f : 0.f; sm.d.wpos[tid] = (tid == 0) ? 1.f : 0.f; }
    __syncthreads();

    for (int tau = 0; tau < S_LEN; ++tau) {
      // prefetch v/k (pre-pass data, flag-independent)
      float vreg = 0.f, kreg = 0.f;
      if (tid < 64)        vreg = ws[VAL_OFF + (size_t)tau * 8192 + n * 256 + tpp * 64 + tid];
      else if (tid < 128)  kreg = ws[KEY_OFF + (size_t)tau * 8192 + n * 256 + tpp * 64 + (tid - 64)];
      // wait: h_tau ready (LSTM flags >= tau+1), sibling ro_{tau-1} ready (tape flags >= tau)
      wait_lstm_flags(lflg, tid, (unsigned)(tau + 1));
      if (tid < 64 && tau > 0) {
        unsigned tgt2 = (unsigned)tau;
        while (true) {
          unsigned a = (tid < 4) ? coh_ldu(tflg + (n * 4 + tid) * 16) : tgt2;
          if (__all(a >= tgt2)) break;
          __builtin_amdgcn_s_sleep(1);
        }
      }
      __syncthreads();
      // stage har = [h_tau | ro_{tau-1}] via agent-scope loads (LLC-fresh)
      {
        // h part: HTA [d][n] layout, 2 scalar loads/thread (d = tid, tid+256)
        const float* hb = ws + HTA_OFF + (size_t)(tau + 1) * 16384 + n;
        sm.d.har[tid]       = coh_ld1(hb + (size_t)tid * 32);
        sm.d.har[tid + 256] = coh_ld1(hb + (size_t)(tid + 256) * 32);
        if (tid < 128) {
          float2 rv = coh_ld2(ws + ROB_OFF + (size_t)tau * 8192 + n * 256 + 2 * tid);
          ((float2*)(sm.d.har + 512))[tid] = rv;
        }
        if (tid < 64) sm.d.v[tid] = vreg;
        else if (tid < 128) sm.d.kr[tid - 64] = kreg;
      }
      __syncthreads();
      // action(10)+query(64) GEMM, K=768, 3-way K-split
      if (tid < 222) {
        int o = tid % 74, ks2 = tid / 74;
        const float4* w4 = (const float4*)(ws + WAQT_OFF + (size_t)(tpp * 74 + o) * 768) + ks2 * 64;
        const float4* h4 = (const float4*)sm.d.har + ks2 * 64;
        float p = 0.f;
#pragma unroll 16
        for (int j = 0; j < 64; ++j) {
          float4 a = w4[j], b = h4[j];
          p += a.x * b.x + a.y * b.y + a.z * b.z + a.w * b.w;
        }
        sm.d.scrA[tid] = p;
      }
      __syncthreads();
      if (tid < 74) {
        float val = sm.d.scrA[tid] + sm.d.scrA[tid + 74] + sm.d.scrA[tid + 148] + ws[BAQ_OFF + tpp * 74 + tid];
        if (tid < 10) sm.d.act[tid] = val;
        else          sm.d.q[tid - 10] = val;
      }
      __syncthreads();
      float rd0, rd1, rd2, rd3, wd0, wd1, wd2, wd3, rw0, rw1;
      {
        float a0 = sm.d.act[0], a1 = sm.d.act[1], a2 = sm.d.act[2], a3 = sm.d.act[3];
        float mx = fmaxf(fmaxf(a0, a1), fmaxf(a2, a3));
        float e0 = expf(a0 - mx), e1 = expf(a1 - mx), e2 = expf(a2 - mx), e3 = expf(a3 - mx);
        float inv = 1.f / (e0 + e1 + e2 + e3);
        rd0 = e0 * inv; rd1 = e1 * inv; rd2 = e2 * inv; rd3 = e3 * inv;
        a0 = sm.d.act[4]; a1 = sm.d.act[5]; a2 = sm.d.act[6]; a3 = sm.d.act[7];
        mx = fmaxf(fmaxf(a0, a1), fmaxf(a2, a3));
        e0 = expf(a0 - mx); e1 = expf(a1 - mx); e2 = expf(a2 - mx); e3 = expf(a3 - mx);
        inv = 1.f / (e0 + e1 + e2 + e3);
        wd0 = e0 * inv; wd1 = e1 * inv; wd2 = e2 * inv; wd3 = e3 * inv;
        rw0 = 1.f / (1.f + expf(-sm.d.act[8]));
        rw1 = 1.f / (1.f + expf(-sm.d.act[9]));
      }
      const int c = tid & 63, ls = tid >> 6;
      {
        float pv = 0.f, pk = 0.f;
#pragma unroll
        for (int i = 0; i < 8; ++i) {
          int l = ls * 8 + i;
          float wp = sm.d.wpos[l];
          pv = fmaf(sm.d.tape[l][c], wp, pv);
          pk = fmaf(sm.d.tkey[l][c], wp, pk);
        }
        sm.d.scrA[tid] = pv; sm.d.scrB[tid] = pk;
      }
      __syncthreads();
      if (tid < 64) {
        float ov = sm.d.scrA[tid] + sm.d.scrA[tid + 64] + sm.d.scrA[tid + 128] + sm.d.scrA[tid + 192];
        float ok = sm.d.scrB[tid] + sm.d.scrB[tid + 64] + sm.d.scrB[tid + 128] + sm.d.scrB[tid + 192];
        sm.d.dv[tid] = (sm.d.v[tid] - ov) * rw1;
        sm.d.dk[tid] = (sm.d.kr[tid] - ok) * rw1;
      }
      __syncthreads();
      {
        float pr = 0.f;
        float dvc = sm.d.dv[c], dkc = sm.d.dk[c];
#pragma unroll
        for (int i = 0; i < 8; ++i) {
          int l = ls * 8 + i;
          float wp = sm.d.wpos[l];
          float tv = sm.d.tape[l][c] + wp * dvc;
          sm.d.tape[l][c] = tv;
          sm.d.tkey[l][c] += wp * dkc;
          pr = fmaf(tv, sm.d.rpos[l], pr);
        }
        sm.d.scrA[tid] = pr;
      }
      __syncthreads();
      float rov = 0.f;
      if (tid < 64)
        rov = (sm.d.scrA[tid] + sm.d.scrA[tid + 64] + sm.d.scrA[tid + 128] + sm.d.scrA[tid + 192]) * rw0;
      {
        int l2 = tid & 31, cs2 = tid >> 5;
        float pj = 0.f;
#pragma unroll
        for (int i = 0; i < 8; ++i) {
          int cc = cs2 * 8 + i;
          pj = fmaf(sm.d.tkey[l2][cc], sm.d.q[cc], pj);
        }
        sm.d.scrB[tid] = pj;
      }
      __syncthreads();
      float jp = 0.f;
      if (tid < 32) {
#pragma unroll
        for (int cs3 = 0; cs3 < 8; ++cs3) jp += sm.d.scrB[cs3 * 32 + tid];
      }
      if (tid < 64) {
        float v2 = (tid < 32) ? jp : 0.f;
        float ss = v2 * v2;
#pragma unroll
        for (int off = 32; off > 0; off >>= 1) ss += __shfl_down(ss, off, 64);
        if (tid == 0) sm.d.norm = fmaxf(sqrtf(ss), 1e-12f);
      }
      __syncthreads();
      if (tid < 32) {
        float jn = jp / sm.d.norm;
        float prv = sm.d.rpos[(tid + 1) & 31];
        float nxt = sm.d.rpos[(tid + 31) & 31];
        float rp = sm.d.rpos[tid], wp = sm.d.wpos[tid];
        sm.d.wpos[tid] = prv * wd0 + wp * wd1 + nxt * wd2 + jn * wd3;
        sm.d.rpos[tid] = prv * rd0 + rp * rd1 + nxt * rd2 + jn * rd3;
      }
      if (tid < 64)
        coh_st(ws + ROB_OFF + (size_t)(tau + 1) * 8192 + n * 256 + tpp * 64 + tid, rov);
      __syncthreads();   // rpos/wpos LDS + ROB stores drained before flag
      if (tid == 0) coh_stu(tflg + g * 16, (unsigned)(tau + 1));
    }
    // final tape write-out
    for (int i = tid; i < 2048; i += 256) {
      int l = i >> 6, cc = i & 63;
      out[4194304 + (size_t)(l * 32 + n) * 256 + tpp * 64 + cc] = sm.d.tape[l][cc];
    }
  }
}

// out[s][n][d] = sum_m ROB[s+1][n][m] * Wo[m][d] + bo[d]; LDS-transposed ro tile
__global__ __launch_bounds__(256) void k_out_gemm(const float* __restrict__ rob, const float* __restrict__ Wo,
                                                  const float* __restrict__ bo, float* __restrict__ out) {
  __shared__ __align__(16) float ro[256 * 32];   // [m][n], XOR-swizzled float4 chunks over n
  int s = blockIdx.x >> 1, dh = blockIdx.x & 1;
  int d = dh * 256 + threadIdx.x;
  const int tid = threadIdx.x;
  const float* src = rob + (size_t)(s + 1) * 8192;   // slot s+1 = read_outs step s
  for (int w = 0; w < 32; ++w) {
    int idx = tid + w * 256;                 // idx = n*256 + m
    int n = idx >> 8, m = idx & 255;
    float v = src[idx];
    ro[m * 32 + ((((n >> 2) ^ (m & 7)) << 2) | (n & 3))] = v;
  }
  __syncthreads();
  float acc[32];
#pragma unroll
  for (int n = 0; n < 32; ++n) acc[n] = 0.f;
  for (int m = 0; m < 256; ++m) {
    float w = Wo[m * 512 + d];
    const float4* rc = (const float4*)(ro + m * 32);
#pragma unroll
    for (int j = 0; j < 8; ++j) {
      float4 r4 = rc[j ^ (m & 7)];
      acc[4 * j + 0] = fmaf(r4.x, w, acc[4 * j + 0]);
      acc[4 * j + 1] = fmaf(r4.y, w, acc[4 * j + 1]);
      acc[4 * j + 2] = fmaf(r4.z, w, acc[4 * j + 2]);
      acc[4 * j + 3] = fmaf(r4.w, w, acc[4 * j + 3]);
    }
  }
  float bd = bo[d];
#pragma unroll
  for (int n = 0; n < 32; ++n) out[(size_t)(s * 32 + n) * 512 + d] = acc[n] + bd;
}

extern "C" void kernel_launch(void* const* d_in, const int* in_sizes, int n_in,
                              void* d_out, int out_size, void* d_ws, size_t ws_size,
                              hipStream_t stream) {
  const float* inp = (const float*)d_in[0];
  const float* Wih = (const float*)d_in[1];
  const float* Whh = (const float*)d_in[2];
  const float* bih = (const float*)d_in[3];
  const float* bhh = (const float*)d_in[4];
  const float* Wa  = (const float*)d_in[5];
  const float* ba  = (const float*)d_in[6];
  const float* Wv  = (const float*)d_in[7];
  const float* bv  = (const float*)d_in[8];
  const float* Wk  = (const float*)d_in[9];
  const float* bk  = (const float*)d_in[10];
  const float* Wq  = (const float*)d_in[11];
  const float* bq  = (const float*)d_in[12];
  const float* Wo  = (const float*)d_in[13];
  const float* bo  = (const float*)d_in[14];
  float* ws = (float*)d_ws;
  float* out = (float*)d_out;

  hipMemsetAsync(ws + HTA_OFF, 0, 16384 * sizeof(float), stream);    // h_{-1} slot
  hipMemsetAsync(ws + ROB_OFF, 0, 8192 * sizeof(float), stream);     // ro_{-1} slot
  hipMemsetAsync(ws + LFLG_OFF, 0, 4096 * sizeof(unsigned), stream); // LFLG + TFLG
  k_prep_waq<<<dim3(296, 3), 256, 0, stream>>>(Wa, ba, Wq, bq, ws);
  k_pre<<<2560, 256, 0, stream>>>(inp, Wih, bih, bhh, Wv, bv, Wk, bk, ws);
  k_knorm<<<8192, 256, 0, stream>>>(ws);

  // Plain launch — kernel uses only flag-spins (no grid.sync), and all 256 blocks
  // fit co-resident (35 KB LDS -> >=3 blocks/CU). Cooperative launch (R5-R7) was
  // the suspected silent-failure point; its return value was never checked.
  nam_coop<<<dim3(256), dim3(256), 0, stream>>>(Whh, ws, out);

  k_out_gemm<<<512, 256, 0, stream>>>(ws + ROB_OFF, Wo, bo, out);
}